// Round 1
// baseline (4059.937 us; speedup 1.0000x reference)
//
#include <hip/hip_runtime.h>
#include <hip/hip_bf16.h>
#include <stdint.h>

#define L_SEQ 2048
#define BATCH 32
#define D_IN 1024
#define DENSE 256
#define HID 128
#define GATES 512   // 4*HID
#define NT 4
#define START_TAG 2
#define STOP_TAG 3
#define IMPOSSIBLE -10000.0f

// ---------------------------------------------------------------------------
// Tiled fp32 GEMM:  C[M,N] = act(A[M,K] * Bw[N,K]^T + bias1[n] (+ bias2[n]))
// Both A and Bw are row-major with K contiguous (the "NT" layout).
// 128x128 tile, BK=16, 256 threads, 8x8 per-thread microtile.
// ---------------------------------------------------------------------------
template<bool RELU, bool DUAL>
__global__ __launch_bounds__(256)
void gemm_nt(const float* __restrict__ A, const float* __restrict__ Bw,
             const float* __restrict__ b1, const float* __restrict__ b2,
             float* __restrict__ C, int M, int N, int K)
{
    __shared__ __align__(16) float As[16][132];
    __shared__ __align__(16) float Bs[16][132];

    const int tid = threadIdx.x;
    const int tx = tid & 15;        // 0..15  -> N direction
    const int ty = tid >> 4;        // 0..15  -> M direction
    const int m0 = blockIdx.x * 128;
    const int n0 = blockIdx.y * 128;

    const int lrow = tid >> 2;          // 0..63
    const int lcol = (tid & 3) * 4;     // 0,4,8,12

    float acc[8][8];
#pragma unroll
    for (int i = 0; i < 8; ++i)
#pragma unroll
        for (int j = 0; j < 8; ++j) acc[i][j] = 0.f;

    for (int k0 = 0; k0 < K; k0 += 16) {
        // stage A,B tiles (transposed: As[k][row])
#pragma unroll
        for (int p = 0; p < 2; ++p) {
            const int row = lrow + p * 64;
            float4 av = *(const float4*)&A[(size_t)(m0 + row) * K + k0 + lcol];
            As[lcol + 0][row] = av.x; As[lcol + 1][row] = av.y;
            As[lcol + 2][row] = av.z; As[lcol + 3][row] = av.w;
            float4 bv = *(const float4*)&Bw[(size_t)(n0 + row) * K + k0 + lcol];
            Bs[lcol + 0][row] = bv.x; Bs[lcol + 1][row] = bv.y;
            Bs[lcol + 2][row] = bv.z; Bs[lcol + 3][row] = bv.w;
        }
        __syncthreads();
#pragma unroll
        for (int kk = 0; kk < 16; ++kk) {
            float a[8], b[8];
            *(float4*)&a[0] = *(const float4*)&As[kk][ty * 8];
            *(float4*)&a[4] = *(const float4*)&As[kk][ty * 8 + 4];
            *(float4*)&b[0] = *(const float4*)&Bs[kk][tx * 8];
            *(float4*)&b[4] = *(const float4*)&Bs[kk][tx * 8 + 4];
#pragma unroll
            for (int i = 0; i < 8; ++i)
#pragma unroll
                for (int j = 0; j < 8; ++j)
                    acc[i][j] = fmaf(a[i], b[j], acc[i][j]);
        }
        __syncthreads();
    }

    // epilogue
    float bia[8];
#pragma unroll
    for (int j = 0; j < 8; ++j) {
        int col = n0 + tx * 8 + j;
        bia[j] = b1[col] + (DUAL ? b2[col] : 0.f);
    }
#pragma unroll
    for (int r = 0; r < 8; ++r) {
        int row = m0 + ty * 8 + r;
        float v[8];
#pragma unroll
        for (int j = 0; j < 8; ++j) {
            v[j] = acc[r][j] + bia[j];
            if (RELU) v[j] = fmaxf(v[j], 0.f);
        }
        float* cp = &C[(size_t)row * N + n0 + tx * 8];
        *(float4*)&cp[0] = make_float4(v[0], v[1], v[2], v[3]);
        *(float4*)&cp[4] = make_float4(v[4], v[5], v[6], v[7]);
    }
}

// ---------------------------------------------------------------------------
// LSTM: one workgroup per (direction, batch). 512 threads; thread t owns gate
// row t of w_hh (128 weights in VGPRs). h/c/g staged in LDS. 2 barriers/step.
// ---------------------------------------------------------------------------
__device__ __forceinline__ float sigf(float x) { return 1.f / (1.f + expf(-x)); }

__global__ __launch_bounds__(512)
void lstm_kernel(const float* __restrict__ preF, const float* __restrict__ preB,
                 const float* __restrict__ wF, const float* __restrict__ wB,
                 float* __restrict__ hF, float* __restrict__ hB)
{
    const int g = blockIdx.x;
    const int dir = g >> 5;          // 0 = fwd, 1 = bwd
    const int b = g & 31;
    const float* pre = dir ? preB : preF;
    const float* W   = dir ? wB : wF;
    float* hout      = dir ? hB : hF;

    const int t = threadIdx.x;       // 0..511 (gate index)

    float w[128];
#pragma unroll
    for (int k = 0; k < 128; k += 4)
        *(float4*)&w[k] = *(const float4*)&W[(size_t)t * 128 + k];

    __shared__ __align__(16) float h_s[128];
    __shared__ __align__(16) float c_s[128];
    __shared__ __align__(16) float g_s[512];

    if (t < 128) { h_s[t] = 0.f; c_s[t] = 0.f; }
    __syncthreads();

    int tt0 = dir ? (L_SEQ - 1) : 0;
    float pre_next = pre[((size_t)tt0 * BATCH + b) * GATES + t];

    for (int step = 0; step < L_SEQ; ++step) {
        const int tt = dir ? (L_SEQ - 1 - step) : step;
        float pre_cur = pre_next;
        if (step + 1 < L_SEQ) {
            int tn = dir ? (L_SEQ - 2 - step) : (step + 1);
            pre_next = pre[((size_t)tn * BATCH + b) * GATES + t];
        }

        float acc = pre_cur;
#pragma unroll
        for (int k = 0; k < 128; k += 4) {
            float4 hv = *(const float4*)&h_s[k];
            acc = fmaf(w[k + 0], hv.x, acc);
            acc = fmaf(w[k + 1], hv.y, acc);
            acc = fmaf(w[k + 2], hv.z, acc);
            acc = fmaf(w[k + 3], hv.w, acc);
        }
        g_s[t] = acc;
        __syncthreads();

        if (t < 128) {
            float iv = g_s[t];
            float fv = g_s[128 + t];
            float gv = g_s[256 + t];
            float ov = g_s[384 + t];
            float c  = sigf(fv) * c_s[t] + sigf(iv) * tanhf(gv);
            float h  = sigf(ov) * tanhf(c);
            c_s[t] = c;
            h_s[t] = h;
            hout[((size_t)tt * BATCH + b) * HID + t] = h;
        }
        __syncthreads();
    }
}

// ---------------------------------------------------------------------------
// Emit: emit[r][c] = dot(hf[r], crf_w[c][0:128]) + dot(hb[r], crf_w[c][128:256]) + crf_b[c]
// thread per (r, c);  r = l*B+b in [0, 65536), c in [0,4)
// ---------------------------------------------------------------------------
__global__ __launch_bounds__(256)
void emit_kernel(const float* __restrict__ hf, const float* __restrict__ hb,
                 const float* __restrict__ crf_w, const float* __restrict__ crf_b,
                 float* __restrict__ emit)
{
    const int idx = blockIdx.x * 256 + threadIdx.x;
    const int r = idx >> 2;
    const int c = idx & 3;
    const float* wf = &crf_w[c * 256];
    float acc = crf_b[c];
#pragma unroll 4
    for (int k = 0; k < 128; k += 4) {
        float4 hv = *(const float4*)&hf[(size_t)r * 128 + k];
        float4 wv = *(const float4*)&wf[k];
        acc = fmaf(hv.x, wv.x, acc); acc = fmaf(hv.y, wv.y, acc);
        acc = fmaf(hv.z, wv.z, acc); acc = fmaf(hv.w, wv.w, acc);
    }
#pragma unroll 4
    for (int k = 0; k < 128; k += 4) {
        float4 hv = *(const float4*)&hb[(size_t)r * 128 + k];
        float4 wv = *(const float4*)&wf[128 + k];
        acc = fmaf(hv.x, wv.x, acc); acc = fmaf(hv.y, wv.y, acc);
        acc = fmaf(hv.z, wv.z, acc); acc = fmaf(hv.w, wv.w, acc);
    }
    emit[idx] = acc;
}

// ---------------------------------------------------------------------------
// Viterbi + backtrace. 2 blocks x 64 threads (one wave). lane = b_loc*4 + i.
// Each block owns 16 batches. bp packed 2-bit x 4 states -> 1 byte per (t,b).
// ---------------------------------------------------------------------------
__global__ __launch_bounds__(64)
void viterbi_kernel(const float* __restrict__ emit, const float* __restrict__ trans,
                    float* __restrict__ out)
{
    const int lane = threadIdx.x;       // 0..63
    const int b_loc = lane >> 2;        // 0..15
    const int i = lane & 3;             // tag
    const int b = blockIdx.x * 16 + b_loc;
    const int base = lane & ~3;

    __shared__ uint8_t bp_s[L_SEQ * 16];
    __shared__ uint8_t tag_s[L_SEQ * 16];

    // per-lane transition row: T[i][j] for j=0..3
    float T0 = trans[i * 4 + 0];
    float T1 = trans[i * 4 + 1];
    float T2 = trans[i * 4 + 2];
    float T3 = trans[i * 4 + 3];
    float tstop = trans[STOP_TAG * 4 + i];

    float s = (i == START_TAG) ? 0.f : IMPOSSIBLE;

    float e_cur = emit[(size_t)0 * BATCH * NT + b * NT + i];
    for (int t = 0; t < L_SEQ; ++t) {
        float e_next = 0.f;
        if (t + 1 < L_SEQ)
            e_next = emit[(size_t)(t + 1) * BATCH * NT + b * NT + i];

        float s0 = __shfl(s, base + 0, 64);
        float s1 = __shfl(s, base + 1, 64);
        float s2 = __shfl(s, base + 2, 64);
        float s3 = __shfl(s, base + 3, 64);

        float a0 = s0 + T0, a1 = s1 + T1, a2 = s2 + T2, a3 = s3 + T3;
        float best = a0; int arg = 0;
        if (a1 > best) { best = a1; arg = 1; }
        if (a2 > best) { best = a2; arg = 2; }
        if (a3 > best) { best = a3; arg = 3; }

        s = best + e_cur;
        e_cur = e_next;

        int A0 = __shfl(arg, base + 0, 64);
        int A1 = __shfl(arg, base + 1, 64);
        int A2 = __shfl(arg, base + 2, 64);
        int A3 = __shfl(arg, base + 3, 64);
        if (i == 0)
            bp_s[t * 16 + b_loc] = (uint8_t)(A0 | (A1 << 2) | (A2 << 4) | (A3 << 6));
    }

    // final scores + argmax (first-max semantics)
    float f = s + tstop;
    float f0 = __shfl(f, base + 0, 64);
    float f1 = __shfl(f, base + 1, 64);
    float f2 = __shfl(f, base + 2, 64);
    float f3 = __shfl(f, base + 3, 64);
    float best = f0; int btag = 0;
    if (f1 > best) { best = f1; btag = 1; }
    if (f2 > best) { best = f2; btag = 2; }
    if (f3 > best) { best = f3; btag = 3; }

    if (i == 0) {
        out[b] = best;
        int tag = btag;
        tag_s[(L_SEQ - 1) * 16 + b_loc] = (uint8_t)tag;
        for (int t = L_SEQ - 1; t >= 1; --t) {
            uint8_t byte = bp_s[t * 16 + b_loc];
            tag = (byte >> (2 * tag)) & 3;
            tag_s[(t - 1) * 16 + b_loc] = (uint8_t)tag;
        }
    }
    __syncthreads();

    // coalesced tag writeout: out[32 + b*L + t]
    float* tout = out + BATCH;
    for (int bb = 0; bb < 16; ++bb) {
        int bg = blockIdx.x * 16 + bb;
        for (int t0 = lane; t0 < L_SEQ; t0 += 64)
            tout[(size_t)bg * L_SEQ + t0] = (float)tag_s[t0 * 16 + bb];
    }
}

// ---------------------------------------------------------------------------
extern "C" void kernel_launch(void* const* d_in, const int* in_sizes, int n_in,
                              void* d_out, int out_size, void* d_ws, size_t ws_size,
                              hipStream_t stream)
{
    const float* src    = (const float*)d_in[0];
    const float* fc1_w  = (const float*)d_in[1];
    const float* fc1_b  = (const float*)d_in[2];
    const float* w_ih_f = (const float*)d_in[3];
    const float* w_hh_f = (const float*)d_in[4];
    const float* b_ih_f = (const float*)d_in[5];
    const float* b_hh_f = (const float*)d_in[6];
    const float* w_ih_b = (const float*)d_in[7];
    const float* w_hh_b = (const float*)d_in[8];
    const float* b_ih_b = (const float*)d_in[9];
    const float* b_hh_b = (const float*)d_in[10];
    const float* crf_w  = (const float*)d_in[11];
    const float* crf_b  = (const float*)d_in[12];
    const float* trans  = (const float*)d_in[13];

    char* ws = (char*)d_ws;
    const size_t MB = 1024 * 1024;
    float* x    = (float*)(ws);              // 64 MB  [65536][256]
    float* preF = (float*)(ws + 64 * MB);    // 128 MB [65536][512]
    float* preB = (float*)(ws + 192 * MB);   // 128 MB [65536][512]
    float* hf   = (float*)(ws);              // 32 MB  (reuse x after pre GEMMs)
    float* hb   = (float*)(ws + 32 * MB);    // 32 MB
    float* emit = (float*)(ws + 64 * MB);    // 1 MB   (reuse preF after LSTM)

    const int M = L_SEQ * BATCH;  // 65536

    // FC1: x = relu(src @ fc1_w^T + fc1_b)
    {
        dim3 grid(M / 128, DENSE / 128);
        gemm_nt<true, false><<<grid, 256, 0, stream>>>(src, fc1_w, fc1_b, nullptr,
                                                       x, M, DENSE, D_IN);
    }
    // pre = x @ w_ih^T + (b_ih + b_hh)
    {
        dim3 grid(M / 128, GATES / 128);
        gemm_nt<false, true><<<grid, 256, 0, stream>>>(x, w_ih_f, b_ih_f, b_hh_f,
                                                       preF, M, GATES, DENSE);
        gemm_nt<false, true><<<grid, 256, 0, stream>>>(x, w_ih_b, b_ih_b, b_hh_b,
                                                       preB, M, GATES, DENSE);
    }
    // LSTM both directions (64 independent chains)
    lstm_kernel<<<64, 512, 0, stream>>>(preF, preB, w_hh_f, w_hh_b, hf, hb);

    // emit
    emit_kernel<<<(M * NT) / 256, 256, 0, stream>>>(hf, hb, crf_w, crf_b, emit);

    // viterbi + backtrace
    viterbi_kernel<<<2, 64, 0, stream>>>(emit, trans, (float*)d_out);
}